// Round 2
// baseline (32.327 us; speedup 1.0000x reference)
//
#include <hip/hip_runtime.h>
#include <math.h>

#define D_IN 512
#define NQ 4
#define QD 6
#define SPW 8   // samples per wave

__device__ __forceinline__ float dot4(float4 a, float4 b) {
    return a.x * b.x + a.y * b.y + a.z * b.z + a.w * b.w;
}

// ---------------------------------------------------------------------------
// Kernel 1: pre-net GEMV + tanh -> half-angles.
// 8 samples per wave. Weights held in registers (loaded once per wave, 4x
// less L1 traffic than per-sample). x loads for all 8 samples issued up
// front (16 outstanding float4 loads -> deep memory-level parallelism).
// Reduction: 10 shuffles/sample (accumulator folding), lane l ends with
// dot(qubit = l&3) -> lanes 0..3 write the 4 half-angles.
// ---------------------------------------------------------------------------
__global__ __launch_bounds__(256, 4) void dqn_gemv(
    const float* __restrict__ x,
    const float* __restrict__ pre_w,
    const float* __restrict__ pre_b,
    float* __restrict__ half_ang,
    int nsamp)
{
    const int lane  = threadIdx.x & 63;
    const int wv    = blockIdx.x * 4 + (threadIdx.x >> 6);
    const int samp0 = wv * SPW;
    if (samp0 >= nsamp) return;

    const float4* xr = reinterpret_cast<const float4*>(x);
    const float4* wr = reinterpret_cast<const float4*>(pre_w);

    // weights: qubit q, halves A (float4 #lane) and B (float4 #lane+64)
    float4 wA[4], wB[4];
#pragma unroll
    for (int q = 0; q < 4; ++q) {
        wA[q] = wr[q * (D_IN / 4) + lane];
        wB[q] = wr[q * (D_IN / 4) + 64 + lane];
    }
    const float bias = pre_b[lane & 3];

    // issue all x loads up front
    float4 xa[SPW], xb[SPW];
#pragma unroll
    for (int j = 0; j < SPW; ++j) {
        const size_t row = (size_t)(samp0 + j) * (D_IN / 4);
        xa[j] = xr[row + lane];
        xb[j] = xr[row + 64 + lane];
    }

#pragma unroll
    for (int j = 0; j < SPW; ++j) {
        float a0 = dot4(xa[j], wA[0]) + dot4(xb[j], wB[0]);
        float a1 = dot4(xa[j], wA[1]) + dot4(xb[j], wB[1]);
        float a2 = dot4(xa[j], wA[2]) + dot4(xb[j], wB[2]);
        float a3 = dot4(xa[j], wA[3]) + dot4(xb[j], wB[3]);

        // fold 4 accumulators -> 1 per lane (lane carries qubit l&3)
        a0 += __shfl_xor(a0, 1, 64);
        a1 += __shfl_xor(a1, 1, 64);
        a2 += __shfl_xor(a2, 1, 64);
        a3 += __shfl_xor(a3, 1, 64);
        float b0 = (lane & 1) ? a1 : a0;
        float b1 = (lane & 1) ? a3 : a2;
        b0 += __shfl_xor(b0, 2, 64);
        b1 += __shfl_xor(b1, 2, 64);
        float c = (lane & 2) ? b1 : b0;
        // allreduce remaining bits -> every lane holds full dot(q = l&3)
        c += __shfl_xor(c, 4, 64);
        c += __shfl_xor(c, 8, 64);
        c += __shfl_xor(c, 16, 64);
        c += __shfl_xor(c, 32, 64);

        float t = c + bias;
        // tanh(t) = 1 - 2/(e^{2t}+1); __expf overflow -> inf -> tanh -> 1 (ok)
        float e = __expf(2.0f * t);
        float th = 1.0f - 2.0f / (e + 1.0f);
        if (lane < 4)
            half_ang[(size_t)(samp0 + j) * 4 + lane] = th * 0.78539816339744831f;
    }
}

// ---------------------------------------------------------------------------
// Kernel 2: 4-qubit statevector sim + post-net. One thread per sample.
// State index: idx = b0*8 + b1*4 + b2*2 + b3 (wire w -> bit (8>>w)).
// H then RY(angle) on all wires == product state:
//   A_w(0) = (c-s)/sqrt2, A_w(1) = (c+s)/sqrt2.
// All loops fully unrolled -> st[16] in registers; CNOT swaps are
// compile-time permutations (zero instructions).
// ---------------------------------------------------------------------------
__global__ __launch_bounds__(256) void dqn_sim(
    const float* __restrict__ half_ang,
    const float* __restrict__ q_params,
    const float* __restrict__ post_w,
    const float* __restrict__ post_b,
    float* __restrict__ out,
    int nsamp)
{
    const int b = blockIdx.x * 256 + threadIdx.x;
    if (b >= nsamp) return;

    float qc[QD][NQ], qs[QD][NQ];
#pragma unroll
    for (int k = 0; k < QD; ++k)
#pragma unroll
        for (int w = 0; w < NQ; ++w)
            __sincosf(q_params[k * NQ + w] * 0.5f, &qs[k][w], &qc[k][w]);

    float4 ha = reinterpret_cast<const float4*>(half_ang)[b];
    float s0, c0, s1, c1, s2, c2, s3, c3;
    __sincosf(ha.x, &s0, &c0);
    __sincosf(ha.y, &s1, &c1);
    __sincosf(ha.z, &s2, &c2);
    __sincosf(ha.w, &s3, &c3);

    const float r2 = 0.70710678118654752f;
    float A0[2] = {(c0 - s0) * r2, (c0 + s0) * r2};
    float A1[2] = {(c1 - s1) * r2, (c1 + s1) * r2};
    float A2[2] = {(c2 - s2) * r2, (c2 + s2) * r2};
    float A3[2] = {(c3 - s3) * r2, (c3 + s3) * r2};

    float u[4], v[4], st[16];
#pragma unroll
    for (int i = 0; i < 4; ++i) { u[i] = A0[i >> 1] * A1[i & 1]; v[i] = A2[i >> 1] * A3[i & 1]; }
#pragma unroll
    for (int i = 0; i < 16; ++i) st[i] = u[i >> 2] * v[i & 3];

#pragma unroll
    for (int k = 0; k < QD; ++k) {
        // CNOT(0,1): b0=1 -> swap b1
#pragma unroll
        for (int j = 0; j < 4; ++j) { float t = st[8 + j]; st[8 + j] = st[12 + j]; st[12 + j] = t; }
        // CNOT(2,3): b2=1 -> swap b3
#pragma unroll
        for (int j = 0; j < 4; ++j) { float t = st[4 * j + 2]; st[4 * j + 2] = st[4 * j + 3]; st[4 * j + 3] = t; }
        // CNOT(1,2): b1=1 -> swap b2
#pragma unroll
        for (int j = 0; j < 2; ++j)
#pragma unroll
            for (int d = 0; d < 2; ++d) {
                const int i0 = j * 8 + 4 + d;
                float t = st[i0]; st[i0] = st[i0 + 2]; st[i0 + 2] = t;
            }
        // RY on each wire
#pragma unroll
        for (int w = 0; w < NQ; ++w) {
            const int m = 8 >> w;
            const float c = qc[k][w], s = qs[k][w];
#pragma unroll
            for (int i = 0; i < 16; ++i) {
                if ((i & m) == 0) {
                    float x0 = st[i], x1 = st[i | m];
                    st[i]     = c * x0 - s * x1;
                    st[i | m] = s * x0 + c * x1;
                }
            }
        }
    }

    float e0 = 0.f, e1 = 0.f, e2 = 0.f, e3 = 0.f;
#pragma unroll
    for (int i = 0; i < 16; ++i) {
        float p = st[i] * st[i];
        e0 += (i & 8) ? -p : p;
        e1 += (i & 4) ? -p : p;
        e2 += (i & 2) ? -p : p;
        e3 += (i & 1) ? -p : p;
    }

    float* orow = out + (size_t)b * 10;
#pragma unroll
    for (int c = 0; c < 10; ++c) {
        orow[c] = post_b[c] + e0 * post_w[c * 4 + 0] + e1 * post_w[c * 4 + 1]
                + e2 * post_w[c * 4 + 2] + e3 * post_w[c * 4 + 3];
    }
}

extern "C" void kernel_launch(void* const* d_in, const int* in_sizes, int n_in,
                              void* d_out, int out_size, void* d_ws, size_t ws_size,
                              hipStream_t stream)
{
    const float* x      = (const float*)d_in[0];
    const float* pre_w  = (const float*)d_in[1];
    const float* pre_b  = (const float*)d_in[2];
    const float* q_par  = (const float*)d_in[3];
    const float* post_w = (const float*)d_in[4];
    const float* post_b = (const float*)d_in[5];
    float* out = (float*)d_out;

    const int nsamp = in_sizes[0] / D_IN;        // 65536
    float* half_ang = (float*)d_ws;              // nsamp*4 floats = 1 MB scratch

    dim3 blk(256);
    const int waves = (nsamp + SPW - 1) / SPW;   // 8192 waves, 1 wave = 8 samples
    dim3 g1((waves + 3) / 4);                    // 4 waves/block
    dqn_gemv<<<g1, blk, 0, stream>>>(x, pre_w, pre_b, half_ang, nsamp);

    dim3 g2((nsamp + 255) / 256);                // 1 thread/sample
    dqn_sim<<<g2, blk, 0, stream>>>(half_ang, q_par, post_w, post_b, out, nsamp);
}

// Round 3
// 29.195 us; speedup vs baseline: 1.1073x; 1.1073x over previous
//
#include <hip/hip_runtime.h>
#include <math.h>

#define D_IN 512
#define NQ 4
#define QD 6
#define SPW 16              // samples per wave (GEMV phase)
#define WPB 4               // waves per block
#define SPB (SPW * WPB)     // 64 samples per block

__device__ __forceinline__ float dot4(float4 a, float4 b) {
    return a.x * b.x + a.y * b.y + a.z * b.z + a.w * b.w;
}

// ---------------------------------------------------------------------------
// Fused kernel.
// Phase 1 (all 4 waves): pre-net GEMV + tanh. Each wave handles 16 samples,
//   weights in registers, x loads batched 8 samples at a time (16 float4 in
//   flight). 10-shuffle fold -> lane l holds dot(qubit=l&3); lanes 0..3 write
//   half-angles to LDS.
// Phase 2 (wave 0 only): threads 0..63 each run the fully-unrolled 4-qubit
//   statevector sim + post-net for one sample. Runs concurrently with other
//   blocks' phase-1 memory traffic (this is the fusion win vs a 2nd kernel
//   at 1 wave/SIMD).
// ---------------------------------------------------------------------------
__global__ __launch_bounds__(256, 4) void dqn_fused(
    const float* __restrict__ x,
    const float* __restrict__ pre_w,
    const float* __restrict__ pre_b,
    const float* __restrict__ q_params,
    const float* __restrict__ post_w,
    const float* __restrict__ post_b,
    float* __restrict__ out,
    int nsamp)
{
    __shared__ float ang[SPB][NQ];   // half-angles, 1 KB

    const int lane = threadIdx.x & 63;
    const int wv   = threadIdx.x >> 6;
    const int blk0 = blockIdx.x * SPB;

    // ---------------- phase 1: GEMV ----------------
    {
        const int s0 = blk0 + wv * SPW;
        if (s0 < nsamp) {
            const float4* xr = reinterpret_cast<const float4*>(x);
            const float4* wr = reinterpret_cast<const float4*>(pre_w);

            float4 wA[4], wB[4];
#pragma unroll
            for (int q = 0; q < 4; ++q) {
                wA[q] = wr[q * (D_IN / 4) + lane];
                wB[q] = wr[q * (D_IN / 4) + 64 + lane];
            }
            const float bias = pre_b[lane & 3];

#pragma unroll
            for (int ch = 0; ch < SPW / 8; ++ch) {
                // batch-issue 16 float4 loads (8 samples)
                float4 xa[8], xb[8];
#pragma unroll
                for (int j = 0; j < 8; ++j) {
                    const size_t row = (size_t)(s0 + ch * 8 + j) * (D_IN / 4);
                    xa[j] = xr[row + lane];
                    xb[j] = xr[row + 64 + lane];
                }
#pragma unroll
                for (int j = 0; j < 8; ++j) {
                    float a0 = dot4(xa[j], wA[0]) + dot4(xb[j], wB[0]);
                    float a1 = dot4(xa[j], wA[1]) + dot4(xb[j], wB[1]);
                    float a2 = dot4(xa[j], wA[2]) + dot4(xb[j], wB[2]);
                    float a3 = dot4(xa[j], wA[3]) + dot4(xb[j], wB[3]);

                    // fold 4 accumulators -> lane carries qubit (lane&3)
                    a0 += __shfl_xor(a0, 1, 64);
                    a1 += __shfl_xor(a1, 1, 64);
                    a2 += __shfl_xor(a2, 1, 64);
                    a3 += __shfl_xor(a3, 1, 64);
                    float b0 = (lane & 1) ? a1 : a0;
                    float b1 = (lane & 1) ? a3 : a2;
                    b0 += __shfl_xor(b0, 2, 64);
                    b1 += __shfl_xor(b1, 2, 64);
                    float c = (lane & 2) ? b1 : b0;
                    c += __shfl_xor(c, 4, 64);
                    c += __shfl_xor(c, 8, 64);
                    c += __shfl_xor(c, 16, 64);
                    c += __shfl_xor(c, 32, 64);

                    float t = c + bias;
                    // tanh(t) = 1 - 2/(e^{2t}+1); __expf inf -> tanh -> 1 (ok)
                    float e = __expf(2.0f * t);
                    float th = 1.0f - 2.0f / (e + 1.0f);
                    if (lane < 4)
                        ang[wv * SPW + ch * 8 + j][lane] = th * 0.78539816339744831f;
                }
            }
        }
    }
    __syncthreads();

    // ---------------- phase 2: sim + post-net (threads 0..63) ----------------
    if (threadIdx.x < SPB) {
        const int t = threadIdx.x;
        const int b = blk0 + t;
        if (b < nsamp) {
            float qc[QD][NQ], qs[QD][NQ];
#pragma unroll
            for (int k = 0; k < QD; ++k)
#pragma unroll
                for (int w = 0; w < NQ; ++w)
                    __sincosf(q_params[k * NQ + w] * 0.5f, &qs[k][w], &qc[k][w]);

            float s0, c0, s1, c1, s2, c2, s3, c3;
            __sincosf(ang[t][0], &s0, &c0);
            __sincosf(ang[t][1], &s1, &c1);
            __sincosf(ang[t][2], &s2, &c2);
            __sincosf(ang[t][3], &s3, &c3);

            const float r2 = 0.70710678118654752f;
            float A0[2] = {(c0 - s0) * r2, (c0 + s0) * r2};
            float A1[2] = {(c1 - s1) * r2, (c1 + s1) * r2};
            float A2[2] = {(c2 - s2) * r2, (c2 + s2) * r2};
            float A3[2] = {(c3 - s3) * r2, (c3 + s3) * r2};

            float u[4], v[4], st[16];
#pragma unroll
            for (int i = 0; i < 4; ++i) { u[i] = A0[i >> 1] * A1[i & 1]; v[i] = A2[i >> 1] * A3[i & 1]; }
#pragma unroll
            for (int i = 0; i < 16; ++i) st[i] = u[i >> 2] * v[i & 3];

#pragma unroll
            for (int k = 0; k < QD; ++k) {
                // CNOT(0,1): b0=1 -> swap b1 (compile-time reg permutation)
#pragma unroll
                for (int j = 0; j < 4; ++j) { float tt = st[8 + j]; st[8 + j] = st[12 + j]; st[12 + j] = tt; }
                // CNOT(2,3): b2=1 -> swap b3
#pragma unroll
                for (int j = 0; j < 4; ++j) { float tt = st[4 * j + 2]; st[4 * j + 2] = st[4 * j + 3]; st[4 * j + 3] = tt; }
                // CNOT(1,2): b1=1 -> swap b2
#pragma unroll
                for (int j = 0; j < 2; ++j)
#pragma unroll
                    for (int d = 0; d < 2; ++d) {
                        const int i0 = j * 8 + 4 + d;
                        float tt = st[i0]; st[i0] = st[i0 + 2]; st[i0 + 2] = tt;
                    }
                // RY on each wire
#pragma unroll
                for (int w = 0; w < NQ; ++w) {
                    const int m = 8 >> w;
                    const float c = qc[k][w], s = qs[k][w];
#pragma unroll
                    for (int i = 0; i < 16; ++i) {
                        if ((i & m) == 0) {
                            float x0 = st[i], x1 = st[i | m];
                            st[i]     = c * x0 - s * x1;
                            st[i | m] = s * x0 + c * x1;
                        }
                    }
                }
            }

            float e0 = 0.f, e1 = 0.f, e2 = 0.f, e3 = 0.f;
#pragma unroll
            for (int i = 0; i < 16; ++i) {
                float p = st[i] * st[i];
                e0 += (i & 8) ? -p : p;
                e1 += (i & 4) ? -p : p;
                e2 += (i & 2) ? -p : p;
                e3 += (i & 1) ? -p : p;
            }

            // post-net; out row is 40B-aligned -> 5x float2 stores
            float r[10];
#pragma unroll
            for (int c = 0; c < 10; ++c) {
                r[c] = post_b[c] + e0 * post_w[c * 4 + 0] + e1 * post_w[c * 4 + 1]
                     + e2 * post_w[c * 4 + 2] + e3 * post_w[c * 4 + 3];
            }
            float2* orow = reinterpret_cast<float2*>(out + (size_t)b * 10);
#pragma unroll
            for (int c = 0; c < 5; ++c)
                orow[c] = make_float2(r[2 * c], r[2 * c + 1]);
        }
    }
}

extern "C" void kernel_launch(void* const* d_in, const int* in_sizes, int n_in,
                              void* d_out, int out_size, void* d_ws, size_t ws_size,
                              hipStream_t stream)
{
    const float* x      = (const float*)d_in[0];
    const float* pre_w  = (const float*)d_in[1];
    const float* pre_b  = (const float*)d_in[2];
    const float* q_par  = (const float*)d_in[3];
    const float* post_w = (const float*)d_in[4];
    const float* post_b = (const float*)d_in[5];
    float* out = (float*)d_out;

    const int nsamp = in_sizes[0] / D_IN;              // 65536
    dim3 blk(256);
    dim3 grid((nsamp + SPB - 1) / SPB);                // 1024 blocks = 4/CU, one round
    dqn_fused<<<grid, blk, 0, stream>>>(x, pre_w, pre_b, q_par, post_w, post_b, out, nsamp);
}